// Round 20
// baseline (196.304 us; speedup 1.0000x reference)
//
#include <hip/hip_runtime.h>
#include <stdint.h>

// SNN: B=1024, D_IN=1024, D_H=2048, D_OUT=256, T=50, beta=0.9, thr=1.0
// cur1 time-invariant -> spk1 precomputable; layer2 = one GEMM over M = T*B.
// R20: R19's prep LDS-transpose re-applied with ALIGNED row stride 136 uint16
// (R19's stride 130 made odd-row uint2/uint4 LDS accesses misaligned -> UB ->
// replay-nondeterminism). lif2 1 elem/thread + prefetch. gemm1lif + gemm2
// (R12-exact, floor 59us) unchanged from R18.

#define BATCH 1024
#define DIN   1024
#define DH    2048
#define DOUT  256
#define TSTEPS 50
#define QS    131072.0f          // 2^17
#define QINVS 7.62939453125e-6f  // 2^-17

typedef __bf16 bf16x8 __attribute__((ext_vector_type(8)));
typedef float  f32x4  __attribute__((ext_vector_type(4)));
typedef int    i32x4  __attribute__((ext_vector_type(4)));
typedef int    i32x16 __attribute__((ext_vector_type(16)));

__device__ __forceinline__ uint16_t f32_bf16_rne(float f) {
  uint32_t u = __float_as_uint(f);
  uint32_t r = u + 0x7FFFu + ((u >> 16) & 1u);
  return (uint16_t)(r >> 16);
}

// expand 16 spike bits -> 16 i8 bytes {0,1}; byte j = bit j
__device__ __forceinline__ i32x4 expand16(uint32_t s) {
  i32x4 r;
  r[0] = (int)((( s        & 0xFu) * 0x00204081u) & 0x01010101u);
  r[1] = (int)((((s >>  4) & 0xFu) * 0x00204081u) & 0x01010101u);
  r[2] = (int)((((s >>  8) & 0xFu) * 0x00204081u) & 0x01010101u);
  r[3] = (int)((((s >> 12) & 0xFu) * 0x00204081u) & 0x01010101u);
  return r;
}

// -------- prep: LDS-transpose pack. Blocks 0..127: x, 128..383: W1 (tile =
// 64 m x 128 k; coalesced k-fast reads -> LDS (stride 136 uint16 = 272B: all
// uint2/uint4 accesses naturally aligned; 2-way banks = free) -> coalesced
// m-fast 16B writes). Blocks 384..511: W2 quantize.
__global__ void prep_kernel(const float* __restrict__ x, const float* __restrict__ W1,
                            const float* __restrict__ W2,
                            uint16_t* __restrict__ PXh, uint16_t* __restrict__ PXl,
                            uint16_t* __restrict__ PWh, uint16_t* __restrict__ PWl,
                            int8_t* __restrict__ PB) {
  int bid = blockIdx.x;
  if (bid < 384) {
    __shared__ __align__(16) uint16_t sh[64 * 136], sl[64 * 136];   // 34.8 KB
    const float* src;
    uint16_t *dh, *dl;
    int m0, kc0; size_t M;
    if (bid < 128) {
      m0 = (bid >> 3) * 64; kc0 = (bid & 7) * 128; M = 1024;
      src = x; dh = PXh; dl = PXl;
    } else {
      int b2 = bid - 128;
      m0 = (b2 >> 3) * 64; kc0 = (b2 & 7) * 128; M = 2048;
      src = W1; dh = PWh; dl = PWl;
    }
    int tid = threadIdx.x;
    // phase 1: 2048 float4 units, k lane-fast (coalesced reads)
#pragma unroll
    for (int ph = 0; ph < 8; ++ph) {
      int u = ph * 256 + tid;
      int m = u >> 5, kf = u & 31;                    // kf = float4 index in 128 k
      float4 v = *(const float4*)(src + (size_t)(m0 + m) * DIN + kc0 + kf * 4);
      float vv[4] = {v.x, v.y, v.z, v.w};
      uint16_t h[4], l[4];
#pragma unroll
      for (int j = 0; j < 4; ++j) {
        h[j] = f32_bf16_rne(vv[j]);
        l[j] = f32_bf16_rne(vv[j] - __uint_as_float((uint32_t)h[j] << 16));
      }
      *(uint2*)&sh[m * 136 + kf * 4] = make_uint2(h[0] | (h[1] << 16), h[2] | (h[3] << 16));
      *(uint2*)&sl[m * 136 + kf * 4] = make_uint2(l[0] | (l[1] << 16), l[2] | (l[3] << 16));
    }
    __syncthreads();
    // phase 2: 1024 write units (ko, m), m lane-fast (coalesced 16B writes)
#pragma unroll
    for (int ph = 0; ph < 4; ++ph) {
      int v = ph * 256 + tid;
      int ko = v >> 6, m = v & 63;
      uint4 hv = *(const uint4*)&sh[m * 136 + ko * 8];
      uint4 lv = *(const uint4*)&sl[m * 136 + ko * 8];
      size_t o = ((size_t)((kc0 >> 3) + ko) * M + m0 + m) * 8;
      *(uint4*)(dh + o) = hv;
      *(uint4*)(dl + o) = lv;
    }
  } else {
    // W2 quantize: q = rint(w*2^17) = hi*256+lo; PB[kc][nb][pass][lane][16B]
    int t = (bid - 384) * 256 + threadIdx.x;  // 32768 threads
    int n = t & 255;
    int k0 = (t >> 8) * 16;
    uint32_t hw[4], lw[4];
#pragma unroll
    for (int g = 0; g < 4; ++g) {
      float4 v = *(const float4*)(W2 + (size_t)n * DH + k0 + g * 4);
      float vv[4] = {v.x, v.y, v.z, v.w};
      uint32_t hb = 0, lb = 0;
#pragma unroll
      for (int j = 0; j < 4; ++j) {
        int q = (int)rintf(vv[j] * QS);
        int h = (q + 128) >> 8;
        int l = q - (h << 8);
        hb |= ((uint32_t)(uint8_t)(int8_t)h) << (8 * j);
        lb |= ((uint32_t)(uint8_t)(int8_t)l) << (8 * j);
      }
      hw[g] = hb; lw[g] = lb;
    }
    int kc = k0 >> 5, kh = (k0 >> 4) & 1, nb = n >> 5;
    int lane = (n & 31) + 32 * kh;
    size_t off = (((size_t)(kc * 8 + nb) * 2 + 0) * 64 + lane) * 16;
    *(uint4*)(PB + off)        = make_uint4(hw[0], hw[1], hw[2], hw[3]);
    *(uint4*)(PB + off + 1024) = make_uint4(lw[0], lw[1], lw[2], lw[3]);
  }
}

// -------- FUSED GEMM1+LIF1 (tc=50): unchanged from R18 --------
__global__ __launch_bounds__(256, 2) void gemm1lif_kernel(
    const uint16_t* __restrict__ PXh, const uint16_t* __restrict__ PXl,
    const uint16_t* __restrict__ PWh, const uint16_t* __restrict__ PWl,
    const float* __restrict__ bias, uint16_t* __restrict__ PAb,
    float* __restrict__ hsum, int RB) {
  __shared__ float sC[64 * 68];
  int tid = threadIdx.x;
  int lane = tid & 63, wave = tid >> 6;
  int wm = (wave >> 1) * 32, wn = (wave & 1) * 32;
  int m0blk = blockIdx.x * 64, n0blk = blockIdx.y * 64;
  int m0 = m0blk + wm, n0 = n0blk + wn;
  int rf = lane & 15;
  int ko = lane >> 4;
  const int AK = 4 * 1024 * 8;
  const int BK = 4 * 2048 * 8;

  const uint16_t* axh = PXh + ((size_t)ko * 1024 + m0 + rf) * 8;
  const uint16_t* axl = PXl + ((size_t)ko * 1024 + m0 + rf) * 8;
  const uint16_t* bwh = PWh + ((size_t)ko * 2048 + n0 + rf) * 8;
  const uint16_t* bwl = PWl + ((size_t)ko * 2048 + n0 + rf) * 8;

  f32x4 acc[2][2] = {};
  bf16x8 ah[2][2], al[2][2], bh[2][2], bl[2][2];
#pragma unroll
  for (int s = 0; s < 2; ++s) {
#pragma unroll
    for (int i = 0; i < 2; ++i) {
      ah[s][i] = *(const bf16x8*)(axh + i * 128);
      al[s][i] = *(const bf16x8*)(axl + i * 128);
      bh[s][i] = *(const bf16x8*)(bwh + i * 128);
      bl[s][i] = *(const bf16x8*)(bwl + i * 128);
    }
    axh += AK; axl += AK; bwh += BK; bwl += BK;
  }
  __builtin_amdgcn_sched_barrier(0);

  for (int kc0 = 0; kc0 < 32; kc0 += 2) {
#pragma unroll
    for (int u = 0; u < 2; ++u) {
#pragma unroll
      for (int i = 0; i < 2; ++i)
#pragma unroll
        for (int j = 0; j < 2; ++j) {
          acc[i][j] = __builtin_amdgcn_mfma_f32_16x16x32_bf16(ah[u][i], bh[u][j], acc[i][j], 0, 0, 0);
          acc[i][j] = __builtin_amdgcn_mfma_f32_16x16x32_bf16(ah[u][i], bl[u][j], acc[i][j], 0, 0, 0);
          acc[i][j] = __builtin_amdgcn_mfma_f32_16x16x32_bf16(al[u][i], bh[u][j], acc[i][j], 0, 0, 0);
        }
      __builtin_amdgcn_sched_barrier(0);
#pragma unroll
      for (int i = 0; i < 2; ++i) {
        ah[u][i] = *(const bf16x8*)(axh + i * 128);
        al[u][i] = *(const bf16x8*)(axl + i * 128);
        bh[u][i] = *(const bf16x8*)(bwh + i * 128);
        bl[u][i] = *(const bf16x8*)(bwl + i * 128);
      }
      axh += AK; axl += AK; bwh += BK; bwl += BK;
      __builtin_amdgcn_sched_barrier(0);
    }
  }

  int cq = (lane >> 4) * 4;
#pragma unroll
  for (int j = 0; j < 2; ++j) {
    int colL = wn + j * 16 + rf;
    float bv = bias[n0blk + colL];
#pragma unroll
    for (int i = 0; i < 2; ++i) {
      int rowL = wm + i * 16 + cq;
#pragma unroll
      for (int r = 0; r < 4; ++r)
        sC[(rowL + r) * 68 + colL] = acc[i][j][r] + bv;
    }
  }
  __syncthreads();

  {
#pragma clang fp contract(off)
    int bL = tid & 63, hg = tid >> 6;
    int b = m0blk + bL;
    int h0 = n0blk + hg * 16;
    float c[16], m[16], hs[16];
#pragma unroll
    for (int g = 0; g < 4; ++g) {
      float4 v = *(const float4*)&sC[bL * 68 + hg * 16 + g * 4];
      c[g * 4] = v.x; c[g * 4 + 1] = v.y; c[g * 4 + 2] = v.z; c[g * 4 + 3] = v.w;
    }
#pragma unroll
    for (int v = 0; v < 16; ++v) { m[v] = 0.0f; hs[v] = 0.0f; }

    int kc = h0 >> 5, kh = (h0 >> 4) & 1;
    int laneP = (b & 31) + 32 * kh;
    uint16_t* pab = PAb + ((size_t)kc * RB + (b >> 5)) * 64 + laneP;

    for (int t = 0; t < TSTEPS; ++t) {
      uint32_t w = 0;
#pragma unroll
      for (int v = 0; v < 16; ++v) {
        float r = (m[v] > 1.0f) ? 1.0f : 0.0f;
        m[v] = 0.9f * m[v] + c[v] - r;
        bool s = (m[v] - 1.0f) > 0.0f;
        hs[v] += s ? 1.0f : 0.0f;
        w |= (s ? 1u : 0u) << v;
      }
      *pab = (uint16_t)w;
      pab += 32 * 64;
    }
#pragma unroll
    for (int g = 0; g < 4; ++g)
      *(float4*)(hsum + (size_t)b * DH + h0 + g * 4) =
          make_float4(hs[g * 4], hs[g * 4 + 1], hs[g * 4 + 2], hs[g * 4 + 3]);
  }
}

// -------- GEMM1 (standalone, fallback path): writes cur1 --------
__global__ __launch_bounds__(256, 2) void gemm1_kernel(
    const uint16_t* __restrict__ PXh, const uint16_t* __restrict__ PXl,
    const uint16_t* __restrict__ PWh, const uint16_t* __restrict__ PWl,
    const float* __restrict__ bias, float* __restrict__ C) {
  const int N = DH;
  int tid = threadIdx.x;
  int lane = tid & 63, wave = tid >> 6;
  int wm = (wave >> 1) * 32, wn = (wave & 1) * 32;
  int m0 = blockIdx.x * 64 + wm;
  int n0 = blockIdx.y * 64 + wn;
  int rf = lane & 15;
  int ko = lane >> 4;
  const int AK = 4 * 1024 * 8;
  const int BK = 4 * 2048 * 8;

  const uint16_t* axh = PXh + ((size_t)ko * 1024 + m0 + rf) * 8;
  const uint16_t* axl = PXl + ((size_t)ko * 1024 + m0 + rf) * 8;
  const uint16_t* bwh = PWh + ((size_t)ko * 2048 + n0 + rf) * 8;
  const uint16_t* bwl = PWl + ((size_t)ko * 2048 + n0 + rf) * 8;

  f32x4 acc[2][2] = {};
  bf16x8 ah[2][2], al[2][2], bh[2][2], bl[2][2];
#pragma unroll
  for (int s = 0; s < 2; ++s) {
#pragma unroll
    for (int i = 0; i < 2; ++i) {
      ah[s][i] = *(const bf16x8*)(axh + i * 128);
      al[s][i] = *(const bf16x8*)(axl + i * 128);
      bh[s][i] = *(const bf16x8*)(bwh + i * 128);
      bl[s][i] = *(const bf16x8*)(bwl + i * 128);
    }
    axh += AK; axl += AK; bwh += BK; bwl += BK;
  }
  __builtin_amdgcn_sched_barrier(0);

  for (int kc0 = 0; kc0 < 32; kc0 += 2) {
#pragma unroll
    for (int u = 0; u < 2; ++u) {
#pragma unroll
      for (int i = 0; i < 2; ++i)
#pragma unroll
        for (int j = 0; j < 2; ++j) {
          acc[i][j] = __builtin_amdgcn_mfma_f32_16x16x32_bf16(ah[u][i], bh[u][j], acc[i][j], 0, 0, 0);
          acc[i][j] = __builtin_amdgcn_mfma_f32_16x16x32_bf16(ah[u][i], bl[u][j], acc[i][j], 0, 0, 0);
          acc[i][j] = __builtin_amdgcn_mfma_f32_16x16x32_bf16(al[u][i], bh[u][j], acc[i][j], 0, 0, 0);
        }
      __builtin_amdgcn_sched_barrier(0);
#pragma unroll
      for (int i = 0; i < 2; ++i) {
        ah[u][i] = *(const bf16x8*)(axh + i * 128);
        al[u][i] = *(const bf16x8*)(axl + i * 128);
        bh[u][i] = *(const bf16x8*)(bwh + i * 128);
        bl[u][i] = *(const bf16x8*)(bwl + i * 128);
      }
      axh += AK; axl += AK; bwh += BK; bwl += BK;
      __builtin_amdgcn_sched_barrier(0);
    }
  }

  int cq = (lane >> 4) * 4;
#pragma unroll
  for (int j = 0; j < 2; ++j) {
    int col = n0 + j * 16 + rf;
    float bv = bias[col];
#pragma unroll
    for (int i = 0; i < 2; ++i) {
      size_t row = m0 + i * 16 + cq;
      float* cp = C + row * N + col;
#pragma unroll
      for (int r = 0; r < 4; ++r) cp[(size_t)r * N] = acc[i][j][r] + bv;
    }
  }
}

// -------- GEMM2 (R12-exact, measured floor ~59us) --------
__global__ __launch_bounds__(256, 3) void gemm2_kernel(
    const uint16_t* __restrict__ PAb, const int8_t* __restrict__ PB,
    const float* __restrict__ bias, float* __restrict__ C, int RB) {
  int tid = threadIdx.x;
  int lane = tid & 63, wave = tid >> 6;
  int bxm = blockIdx.x;
  int nb  = blockIdx.y;

  const uint16_t* pa = PAb + (size_t)(bxm * 8 + wave * 2) * 64 + lane;
  const int8_t*   pb = PB + ((size_t)nb * 2 * 64 + lane) * 16;
  size_t strideA = (size_t)RB * 64;

  i32x16 acch[2] = {};
  i32x16 accl[2] = {};

  uint16_t abit[4][2];
  i32x4 bbh[4], bbl[4];
  i32x4 aexp[2][2];

#pragma unroll
  for (int u = 0; u < 4; ++u) {
#pragma unroll
    for (int mi = 0; mi < 2; ++mi) abit[u][mi] = pa[mi * 64];
    bbh[u] = *(const i32x4*)(pb);
    bbl[u] = *(const i32x4*)(pb + 1024);
    pa += strideA; pb += 16384;
  }
#pragma unroll
  for (int mi = 0; mi < 2; ++mi) aexp[0][mi] = expand16(abit[0][mi]);
  __builtin_amdgcn_sched_barrier(0);

  for (int kc0 = 0; kc0 < 64; kc0 += 4) {
#pragma unroll
    for (int u = 0; u < 4; ++u) {
      const int p = u & 1;
#pragma unroll
      for (int mi = 0; mi < 2; ++mi) aexp[p ^ 1][mi] = expand16(abit[(u + 1) & 3][mi]);
#pragma unroll
      for (int mi = 0; mi < 2; ++mi) {
        acch[mi] = __builtin_amdgcn_mfma_i32_32x32x32_i8(aexp[p][mi], bbh[u], acch[mi], 0, 0, 0);
        accl[mi] = __builtin_amdgcn_mfma_i32_32x32x32_i8(aexp[p][mi], bbl[u], accl[mi], 0, 0, 0);
      }
      __builtin_amdgcn_sched_barrier(0);
#pragma unroll
      for (int mi = 0; mi < 2; ++mi) abit[u][mi] = pa[mi * 64];
      bbh[u] = *(const i32x4*)(pb);
      bbl[u] = *(const i32x4*)(pb + 1024);
      pa += strideA; pb += 16384;
      __builtin_amdgcn_sched_barrier(0);
    }
  }

  int rm = lane & 31, half = lane >> 5;
  int col = nb * 32 + rm;
  float bv = bias[col];
#pragma unroll
  for (int mi = 0; mi < 2; ++mi) {
#pragma unroll
    for (int r = 0; r < 16; ++r) {
      int row = bxm * 256 + wave * 64 + mi * 32 + (r & 3) + 8 * (r >> 2) + 4 * half;
      int q = acch[mi][r] * 256 + accl[mi][r];
      C[(size_t)row * DOUT + col] = (float)q * QINVS + bv;
    }
  }
}

// -------- LIF layer 1 (fallback path only, tc<50) --------
__global__ void lif1_kernel(const float* __restrict__ cur1, float* __restrict__ mem1,
                            uint16_t* __restrict__ PAb, float* __restrict__ hsum,
                            int tc, int init, int save_mem, int RB) {
#pragma clang fp contract(off)
  int idx = blockIdx.x * 256 + threadIdx.x;
  int b = idx & 1023;
  int h0 = (idx >> 10) * 16;
  size_t e0 = (size_t)b * DH + h0;

  float m[16], c[16], hs[16];
#pragma unroll
  for (int g = 0; g < 4; ++g) {
    float4 v = *(const float4*)(cur1 + e0 + g * 4);
    c[g * 4] = v.x; c[g * 4 + 1] = v.y; c[g * 4 + 2] = v.z; c[g * 4 + 3] = v.w;
  }
#pragma unroll
  for (int v = 0; v < 16; ++v) { m[v] = 0.0f; hs[v] = 0.0f; }
  if (!init) {
#pragma unroll
    for (int g = 0; g < 4; ++g) {
      float4 v = *(const float4*)(mem1 + e0 + g * 4);
      m[g * 4] = v.x; m[g * 4 + 1] = v.y; m[g * 4 + 2] = v.z; m[g * 4 + 3] = v.w;
    }
  }

  int kc = h0 >> 5, kh = (h0 >> 4) & 1;
  int lane = (b & 31) + 32 * kh;
  uint16_t* pab = PAb + ((size_t)kc * RB + (b >> 5)) * 64 + lane;

  for (int t = 0; t < tc; ++t) {
    uint32_t w = 0;
#pragma unroll
    for (int v = 0; v < 16; ++v) {
      float r = (m[v] > 1.0f) ? 1.0f : 0.0f;
      m[v] = 0.9f * m[v] + c[v] - r;
      bool s = (m[v] - 1.0f) > 0.0f;
      hs[v] += s ? 1.0f : 0.0f;
      w |= (s ? 1u : 0u) << v;
    }
    *pab = (uint16_t)w;
    pab += 32 * 64;
  }

  if (save_mem) {
#pragma unroll
    for (int g = 0; g < 4; ++g)
      *(float4*)(mem1 + e0 + g * 4) = make_float4(m[g * 4], m[g * 4 + 1], m[g * 4 + 2], m[g * 4 + 3]);
  }
  if (init) {
#pragma unroll
    for (int g = 0; g < 4; ++g)
      *(float4*)(hsum + e0 + g * 4) = make_float4(hs[g * 4], hs[g * 4 + 1], hs[g * 4 + 2], hs[g * 4 + 3]);
  } else {
#pragma unroll
    for (int g = 0; g < 4; ++g) {
      float4 v = *(float4*)(hsum + e0 + g * 4);
      v.x += hs[g * 4]; v.y += hs[g * 4 + 1]; v.z += hs[g * 4 + 2]; v.w += hs[g * 4 + 3];
      *(float4*)(hsum + e0 + g * 4) = v;
    }
  }
}

// -------- LIF layer 2: 1 elem/thread (1024 blocks, 4 waves/SIMD) + prefetch --------
__global__ void lif2_kernel(const float* __restrict__ cur2, float* __restrict__ mem2,
                            float* __restrict__ osum, int tc, int init, int save_mem) {
#pragma clang fp contract(off)
  int idx = blockIdx.x * 256 + threadIdx.x;   // 262144 threads
  float m = init ? 0.0f : mem2[idx];
  float os = 0.0f;
  float nv = cur2[idx];                        // prefetch t=0
  for (int t = 0; t < tc; ++t) {
    float c = nv;
    int tn = (t + 1 < tc) ? (t + 1) : t;
    nv = cur2[(size_t)tn * (BATCH * DOUT) + idx];   // prefetch next (dup on last)
    float r = (m > 1.0f) ? 1.0f : 0.0f;
    m = 0.9f * m + c - r;
    os += ((m - 1.0f) > 0.0f) ? 1.0f : 0.0f;
  }
  if (save_mem) mem2[idx] = m;
  osum[idx] = init ? os : (osum[idx] + os);
}

extern "C" void kernel_launch(void* const* d_in, const int* in_sizes, int n_in,
                              void* d_out, int out_size, void* d_ws, size_t ws_size,
                              hipStream_t stream) {
  const float* x  = (const float*)d_in[0];
  const float* W1 = (const float*)d_in[1];
  const float* b1 = (const float*)d_in[2];
  const float* W2 = (const float*)d_in[3];
  const float* b2 = (const float*)d_in[4];
  float* out = (float*)d_out;           // h_sum [1024*2048] then out_sum [1024*256]
  char* ws = (char*)d_ws;

  const size_t fixed = 36 * 1024 * 1024;
  const size_t perT  = 262144 + 1048576;   // PAb bits + cur2c per time step
  int tc = 10;
  if (ws_size >= fixed + 50ull * perT) tc = 50;
  else if (ws_size >= fixed + 25ull * perT) tc = 25;
  int nchunk = TSTEPS / tc;
  int RB = tc * 32;

  size_t off = 0;
  auto alloc = [&](size_t b) { size_t p = off; off = (off + b + 255) & ~(size_t)255; return p; };
  uint16_t* PXh  = (uint16_t*)(ws + alloc(2097152));
  uint16_t* PXl  = (uint16_t*)(ws + alloc(2097152));
  uint16_t* PWh  = (uint16_t*)(ws + alloc(4194304));
  uint16_t* PWl  = (uint16_t*)(ws + alloc(4194304));
  int8_t*   PB   = (int8_t*)(ws + alloc(1048576 + 262144));          // + pipeline pad
  float*    cur1 = (float*)(ws + alloc(8388608));
  float*    mem1 = (float*)(ws + alloc(8388608));
  float*    mem2 = (float*)(ws + alloc(1048576));
  uint16_t* PAb  = (uint16_t*)(ws + alloc((size_t)tc * 262144 + 4ull * RB * 128)); // + 4-kc pad
  float*    cur2c = (float*)(ws + alloc((size_t)tc * BATCH * DOUT * 4));

  prep_kernel<<<512, 256, 0, stream>>>(x, W1, W2, PXh, PXl, PWh, PWl, PB);

  if (nchunk == 1) {
    // fused path: 4 dispatches total
    gemm1lif_kernel<<<dim3(16, 32), 256, 0, stream>>>(PXh, PXl, PWh, PWl, b1, PAb, out, RB);
    gemm2_kernel<<<dim3((tc * BATCH) / 256, 8), 256, 0, stream>>>(PAb, PB, b2, cur2c, RB);
    lif2_kernel<<<(BATCH * DOUT) / 256, 256, 0, stream>>>(
        cur2c, mem2, out + BATCH * DH, tc, 1, 0);
  } else {
    hipMemsetAsync(mem1, 0, 8388608, stream);
    hipMemsetAsync(mem2, 0, 1048576, stream);
    gemm1_kernel<<<dim3(16, 32), 256, 0, stream>>>(PXh, PXl, PWh, PWl, b1, cur1);
    for (int c = 0; c < nchunk; ++c) {
      int init = (c == 0) ? 1 : 0;
      lif1_kernel<<<(BATCH * DH) / (256 * 16), 256, 0, stream>>>(
          cur1, mem1, PAb, out, tc, init, 1, RB);
      gemm2_kernel<<<dim3((tc * BATCH) / 256, 8), 256, 0, stream>>>(PAb, PB, b2, cur2c, RB);
      lif2_kernel<<<(BATCH * DOUT) / 256, 256, 0, stream>>>(
          cur2c, mem2, out + BATCH * DH, tc, init, 1);
    }
  }
}

// Round 21
// 187.182 us; speedup vs baseline: 1.0487x; 1.0487x over previous
//
#include <hip/hip_runtime.h>
#include <stdint.h>

// SNN: B=1024, D_IN=1024, D_H=2048, D_OUT=256, T=50, beta=0.9, thr=1.0
// cur1 time-invariant -> spk1 precomputable; layer2 = one GEMM over M = T*B.
// R21: exact revert to R18, the best-measured configuration (186.5us).
// - prep: R14 simple form (coalesced writes, strided reads - measured better
//   than R20's LDS-transpose which cost occupancy)
// - gemm1+lif1 fused (cur1 never hits global memory)
// - gemm2: R12-exact bit-A zero-LDS depth-4 fenced pipeline (floor ~59us,
//   measured 5x; retile/depth-8/full-unroll all failed to beat it)
// - lif2: 4 outputs/thread (R14 form; R20's 1-elem split regressed)

#define BATCH 1024
#define DIN   1024
#define DH    2048
#define DOUT  256
#define TSTEPS 50
#define QS    131072.0f          // 2^17
#define QINVS 7.62939453125e-6f  // 2^-17

typedef __bf16 bf16x8 __attribute__((ext_vector_type(8)));
typedef float  f32x4  __attribute__((ext_vector_type(4)));
typedef int    i32x4  __attribute__((ext_vector_type(4)));
typedef int    i32x16 __attribute__((ext_vector_type(16)));

__device__ __forceinline__ uint16_t f32_bf16_rne(float f) {
  uint32_t u = __float_as_uint(f);
  uint32_t r = u + 0x7FFFu + ((u >> 16) & 1u);
  return (uint16_t)(r >> 16);
}

// expand 16 spike bits -> 16 i8 bytes {0,1}; byte j = bit j
__device__ __forceinline__ i32x4 expand16(uint32_t s) {
  i32x4 r;
  r[0] = (int)((( s        & 0xFu) * 0x00204081u) & 0x01010101u);
  r[1] = (int)((((s >>  4) & 0xFu) * 0x00204081u) & 0x01010101u);
  r[2] = (int)((((s >>  8) & 0xFu) * 0x00204081u) & 0x01010101u);
  r[3] = (int)((((s >> 12) & 0xFu) * 0x00204081u) & 0x01010101u);
  return r;
}

// -------- prep: pack x,W1 splits to [k-octet][row][8bf16]; quantize W2 to PB.
// Row index lane-fast -> coalesced writes (R14). Bit-identical math.
__global__ void prep_kernel(const float* __restrict__ x, const float* __restrict__ W1,
                            const float* __restrict__ W2,
                            uint16_t* __restrict__ PXh, uint16_t* __restrict__ PXl,
                            uint16_t* __restrict__ PWh, uint16_t* __restrict__ PWl,
                            int8_t* __restrict__ PB) {
  int bid = blockIdx.x;
  if (bid < 1536) {
    const float* src;
    uint16_t *dh, *dl;
    int m, ko; size_t M;
    if (bid < 512) {
      int t = bid * 256 + threadIdx.x;        // 131072 threads
      m = t & 1023; ko = t >> 10; M = 1024;   // m fast -> coalesced writes
      src = x + (size_t)m * DIN + ko * 8;
      dh = PXh; dl = PXl;
    } else {
      int t = (bid - 512) * 256 + threadIdx.x; // 262144 threads
      m = t & 2047; ko = t >> 11; M = 2048;
      src = W1 + (size_t)m * DIN + ko * 8;
      dh = PWh; dl = PWl;
    }
    float4 a = *(const float4*)(src);
    float4 b = *(const float4*)(src + 4);
    float v[8] = {a.x, a.y, a.z, a.w, b.x, b.y, b.z, b.w};
    uint16_t h[8], l[8];
#pragma unroll
    for (int j = 0; j < 8; ++j) {
      h[j] = f32_bf16_rne(v[j]);
      l[j] = f32_bf16_rne(v[j] - __uint_as_float((uint32_t)h[j] << 16));
    }
    size_t o = ((size_t)ko * M + m) * 8;
    *(uint4*)(dh + o) = make_uint4(h[0] | (h[1] << 16), h[2] | (h[3] << 16),
                                   h[4] | (h[5] << 16), h[6] | (h[7] << 16));
    *(uint4*)(dl + o) = make_uint4(l[0] | (l[1] << 16), l[2] | (l[3] << 16),
                                   l[4] | (l[5] << 16), l[6] | (l[7] << 16));
  } else {
    int t = (bid - 1536) * 256 + threadIdx.x;  // 32768 threads
    int n = t & 255;
    int k0 = (t >> 8) * 16;
    uint32_t hw[4], lw[4];
#pragma unroll
    for (int g = 0; g < 4; ++g) {
      float4 v = *(const float4*)(W2 + (size_t)n * DH + k0 + g * 4);
      float vv[4] = {v.x, v.y, v.z, v.w};
      uint32_t hb = 0, lb = 0;
#pragma unroll
      for (int j = 0; j < 4; ++j) {
        int q = (int)rintf(vv[j] * QS);
        int h = (q + 128) >> 8;
        int l = q - (h << 8);
        hb |= ((uint32_t)(uint8_t)(int8_t)h) << (8 * j);
        lb |= ((uint32_t)(uint8_t)(int8_t)l) << (8 * j);
      }
      hw[g] = hb; lw[g] = lb;
    }
    int kc = k0 >> 5, kh = (k0 >> 4) & 1, nb = n >> 5;
    int lane = (n & 31) + 32 * kh;
    size_t off = (((size_t)(kc * 8 + nb) * 2 + 0) * 64 + lane) * 16;
    *(uint4*)(PB + off)        = make_uint4(hw[0], hw[1], hw[2], hw[3]);
    *(uint4*)(PB + off + 1024) = make_uint4(lw[0], lw[1], lw[2], lw[3]);
  }
}

// -------- FUSED GEMM1+LIF1 (tc=50): cur1 = x @ W1^T + b1 (bf16x3, zero-LDS,
// depth-2 fenced pipeline, bit-identical MFMA order), then LDS-transpose the
// C fragments and run the 50-step LIF recurrence per thread, emitting spike
// bits + h_sum directly. cur1 never touches global memory.
__global__ __launch_bounds__(256, 2) void gemm1lif_kernel(
    const uint16_t* __restrict__ PXh, const uint16_t* __restrict__ PXl,
    const uint16_t* __restrict__ PWh, const uint16_t* __restrict__ PWl,
    const float* __restrict__ bias, uint16_t* __restrict__ PAb,
    float* __restrict__ hsum, int RB) {
  __shared__ float sC[64 * 68];          // stride 68: 16B-aligned rows, 17KB
  int tid = threadIdx.x;
  int lane = tid & 63, wave = tid >> 6;
  int wm = (wave >> 1) * 32, wn = (wave & 1) * 32;
  int m0blk = blockIdx.x * 64, n0blk = blockIdx.y * 64;
  int m0 = m0blk + wm, n0 = n0blk + wn;
  int rf = lane & 15;
  int ko = lane >> 4;
  const int AK = 4 * 1024 * 8;
  const int BK = 4 * 2048 * 8;

  const uint16_t* axh = PXh + ((size_t)ko * 1024 + m0 + rf) * 8;
  const uint16_t* axl = PXl + ((size_t)ko * 1024 + m0 + rf) * 8;
  const uint16_t* bwh = PWh + ((size_t)ko * 2048 + n0 + rf) * 8;
  const uint16_t* bwl = PWl + ((size_t)ko * 2048 + n0 + rf) * 8;

  f32x4 acc[2][2] = {};
  bf16x8 ah[2][2], al[2][2], bh[2][2], bl[2][2];
#pragma unroll
  for (int s = 0; s < 2; ++s) {
#pragma unroll
    for (int i = 0; i < 2; ++i) {
      ah[s][i] = *(const bf16x8*)(axh + i * 128);
      al[s][i] = *(const bf16x8*)(axl + i * 128);
      bh[s][i] = *(const bf16x8*)(bwh + i * 128);
      bl[s][i] = *(const bf16x8*)(bwl + i * 128);
    }
    axh += AK; axl += AK; bwh += BK; bwl += BK;
  }
  __builtin_amdgcn_sched_barrier(0);

  for (int kc0 = 0; kc0 < 32; kc0 += 2) {
#pragma unroll
    for (int u = 0; u < 2; ++u) {
#pragma unroll
      for (int i = 0; i < 2; ++i)
#pragma unroll
        for (int j = 0; j < 2; ++j) {
          acc[i][j] = __builtin_amdgcn_mfma_f32_16x16x32_bf16(ah[u][i], bh[u][j], acc[i][j], 0, 0, 0);
          acc[i][j] = __builtin_amdgcn_mfma_f32_16x16x32_bf16(ah[u][i], bl[u][j], acc[i][j], 0, 0, 0);
          acc[i][j] = __builtin_amdgcn_mfma_f32_16x16x32_bf16(al[u][i], bh[u][j], acc[i][j], 0, 0, 0);
        }
      __builtin_amdgcn_sched_barrier(0);
#pragma unroll
      for (int i = 0; i < 2; ++i) {
        ah[u][i] = *(const bf16x8*)(axh + i * 128);
        al[u][i] = *(const bf16x8*)(axl + i * 128);
        bh[u][i] = *(const bf16x8*)(bwh + i * 128);
        bl[u][i] = *(const bf16x8*)(bwl + i * 128);
      }
      axh += AK; axl += AK; bwh += BK; bwl += BK;
      __builtin_amdgcn_sched_barrier(0);
    }
  }

  // ---- epilogue: C/D 16x16 (col=lane&15, row=(lane>>4)*4+reg) + bias -> LDS ----
  int cq = (lane >> 4) * 4;
#pragma unroll
  for (int j = 0; j < 2; ++j) {
    int colL = wn + j * 16 + rf;
    float bv = bias[n0blk + colL];
#pragma unroll
    for (int i = 0; i < 2; ++i) {
      int rowL = wm + i * 16 + cq;
#pragma unroll
      for (int r = 0; r < 4; ++r)
        sC[(rowL + r) * 68 + colL] = acc[i][j][r] + bv;
    }
  }
  __syncthreads();

  // ---- per-thread LIF recurrence: b = m0blk + (tid&63), h = n0blk + (tid>>6)*16 ----
  {
#pragma clang fp contract(off)
    int bL = tid & 63, hg = tid >> 6;
    int b = m0blk + bL;
    int h0 = n0blk + hg * 16;
    float c[16], m[16], hs[16];
#pragma unroll
    for (int g = 0; g < 4; ++g) {
      float4 v = *(const float4*)&sC[bL * 68 + hg * 16 + g * 4];
      c[g * 4] = v.x; c[g * 4 + 1] = v.y; c[g * 4 + 2] = v.z; c[g * 4 + 3] = v.w;
    }
#pragma unroll
    for (int v = 0; v < 16; ++v) { m[v] = 0.0f; hs[v] = 0.0f; }

    int kc = h0 >> 5, kh = (h0 >> 4) & 1;
    int laneP = (b & 31) + 32 * kh;
    uint16_t* pab = PAb + ((size_t)kc * RB + (b >> 5)) * 64 + laneP;

    for (int t = 0; t < TSTEPS; ++t) {
      uint32_t w = 0;
#pragma unroll
      for (int v = 0; v < 16; ++v) {
        float r = (m[v] > 1.0f) ? 1.0f : 0.0f;   // reset from PREVIOUS mem
        m[v] = 0.9f * m[v] + c[v] - r;           // contract(off): mul,add,sub like np
        bool s = (m[v] - 1.0f) > 0.0f;
        hs[v] += s ? 1.0f : 0.0f;
        w |= (s ? 1u : 0u) << v;                 // bit v = spike(h0+v)
      }
      *pab = (uint16_t)w;
      pab += 32 * 64;                            // +32 rb per t
    }
#pragma unroll
    for (int g = 0; g < 4; ++g)
      *(float4*)(hsum + (size_t)b * DH + h0 + g * 4) =
          make_float4(hs[g * 4], hs[g * 4 + 1], hs[g * 4 + 2], hs[g * 4 + 3]);
  }
}

// -------- GEMM1 (standalone, fallback path): writes cur1 --------
__global__ __launch_bounds__(256, 2) void gemm1_kernel(
    const uint16_t* __restrict__ PXh, const uint16_t* __restrict__ PXl,
    const uint16_t* __restrict__ PWh, const uint16_t* __restrict__ PWl,
    const float* __restrict__ bias, float* __restrict__ C) {
  const int N = DH;
  int tid = threadIdx.x;
  int lane = tid & 63, wave = tid >> 6;
  int wm = (wave >> 1) * 32, wn = (wave & 1) * 32;
  int m0 = blockIdx.x * 64 + wm;
  int n0 = blockIdx.y * 64 + wn;
  int rf = lane & 15;
  int ko = lane >> 4;
  const int AK = 4 * 1024 * 8;
  const int BK = 4 * 2048 * 8;

  const uint16_t* axh = PXh + ((size_t)ko * 1024 + m0 + rf) * 8;
  const uint16_t* axl = PXl + ((size_t)ko * 1024 + m0 + rf) * 8;
  const uint16_t* bwh = PWh + ((size_t)ko * 2048 + n0 + rf) * 8;
  const uint16_t* bwl = PWl + ((size_t)ko * 2048 + n0 + rf) * 8;

  f32x4 acc[2][2] = {};
  bf16x8 ah[2][2], al[2][2], bh[2][2], bl[2][2];
#pragma unroll
  for (int s = 0; s < 2; ++s) {
#pragma unroll
    for (int i = 0; i < 2; ++i) {
      ah[s][i] = *(const bf16x8*)(axh + i * 128);
      al[s][i] = *(const bf16x8*)(axl + i * 128);
      bh[s][i] = *(const bf16x8*)(bwh + i * 128);
      bl[s][i] = *(const bf16x8*)(bwl + i * 128);
    }
    axh += AK; axl += AK; bwh += BK; bwl += BK;
  }
  __builtin_amdgcn_sched_barrier(0);

  for (int kc0 = 0; kc0 < 32; kc0 += 2) {
#pragma unroll
    for (int u = 0; u < 2; ++u) {
#pragma unroll
      for (int i = 0; i < 2; ++i)
#pragma unroll
        for (int j = 0; j < 2; ++j) {
          acc[i][j] = __builtin_amdgcn_mfma_f32_16x16x32_bf16(ah[u][i], bh[u][j], acc[i][j], 0, 0, 0);
          acc[i][j] = __builtin_amdgcn_mfma_f32_16x16x32_bf16(ah[u][i], bl[u][j], acc[i][j], 0, 0, 0);
          acc[i][j] = __builtin_amdgcn_mfma_f32_16x16x32_bf16(al[u][i], bh[u][j], acc[i][j], 0, 0, 0);
        }
      __builtin_amdgcn_sched_barrier(0);
#pragma unroll
      for (int i = 0; i < 2; ++i) {
        ah[u][i] = *(const bf16x8*)(axh + i * 128);
        al[u][i] = *(const bf16x8*)(axl + i * 128);
        bh[u][i] = *(const bf16x8*)(bwh + i * 128);
        bl[u][i] = *(const bf16x8*)(bwl + i * 128);
      }
      axh += AK; axl += AK; bwh += BK; bwl += BK;
      __builtin_amdgcn_sched_barrier(0);
    }
  }

  int cq = (lane >> 4) * 4;
#pragma unroll
  for (int j = 0; j < 2; ++j) {
    int col = n0 + j * 16 + rf;
    float bv = bias[col];
#pragma unroll
    for (int i = 0; i < 2; ++i) {
      size_t row = m0 + i * 16 + cq;
      float* cp = C + row * N + col;
#pragma unroll
      for (int r = 0; r < 4; ++r) cp[(size_t)r * N] = acc[i][j][r] + bv;
    }
  }
}

// -------- GEMM2 (R12-exact, measured floor ~59us): bit-A, zero-LDS, depth-4
// fenced pipeline, wave = 64m x 32n. Block = 4 waves m-stacked = 256m x 32n
// (B block-uniform -> L1-shared). Grid (200 m, 8 nb), 3 blocks/CU.
__global__ __launch_bounds__(256, 3) void gemm2_kernel(
    const uint16_t* __restrict__ PAb, const int8_t* __restrict__ PB,
    const float* __restrict__ bias, float* __restrict__ C, int RB) {
  int tid = threadIdx.x;
  int lane = tid & 63, wave = tid >> 6;   // wave = m-quarter (64 rows)
  int bxm = blockIdx.x;                   // m-group (256 rows = 8 rb)
  int nb  = blockIdx.y;                   // n-group (32 cols)

  const uint16_t* pa = PAb + (size_t)(bxm * 8 + wave * 2) * 64 + lane;
  const int8_t*   pb = PB + ((size_t)nb * 2 * 64 + lane) * 16;
  size_t strideA = (size_t)RB * 64;       // uint16 elems per kc

  i32x16 acch[2] = {};
  i32x16 accl[2] = {};

  uint16_t abit[4][2];
  i32x4 bbh[4], bbl[4];
  i32x4 aexp[2][2];

#pragma unroll
  for (int u = 0; u < 4; ++u) {           // prologue: kc = 0..3
#pragma unroll
    for (int mi = 0; mi < 2; ++mi) abit[u][mi] = pa[mi * 64];
    bbh[u] = *(const i32x4*)(pb);
    bbl[u] = *(const i32x4*)(pb + 1024);
    pa += strideA; pb += 16384;
  }
#pragma unroll
  for (int mi = 0; mi < 2; ++mi) aexp[0][mi] = expand16(abit[0][mi]);
  __builtin_amdgcn_sched_barrier(0);

  for (int kc0 = 0; kc0 < 64; kc0 += 4) {
#pragma unroll
    for (int u = 0; u < 4; ++u) {
      const int p = u & 1;
      // expand next slot's bits (independent of this slot's MFMAs -> overlaps)
#pragma unroll
      for (int mi = 0; mi < 2; ++mi) aexp[p ^ 1][mi] = expand16(abit[(u + 1) & 3][mi]);
      // 4 MFMAs using this slot's pre-expanded A
#pragma unroll
      for (int mi = 0; mi < 2; ++mi) {
        acch[mi] = __builtin_amdgcn_mfma_i32_32x32x32_i8(aexp[p][mi], bbh[u], acch[mi], 0, 0, 0);
        accl[mi] = __builtin_amdgcn_mfma_i32_32x32x32_i8(aexp[p][mi], bbl[u], accl[mi], 0, 0, 0);
      }
      __builtin_amdgcn_sched_barrier(0);
      // prefetch kc0+u+4 into slot u (reads ws pad on the final round)
#pragma unroll
      for (int mi = 0; mi < 2; ++mi) abit[u][mi] = pa[mi * 64];
      bbh[u] = *(const i32x4*)(pb);
      bbl[u] = *(const i32x4*)(pb + 1024);
      pa += strideA; pb += 16384;
      __builtin_amdgcn_sched_barrier(0);
    }
  }

  // C/D 32x32: col = lane&31, row = (r&3) + 8*(r>>2) + 4*(lane>>5)
  int rm = lane & 31, half = lane >> 5;
  int col = nb * 32 + rm;
  float bv = bias[col];
#pragma unroll
  for (int mi = 0; mi < 2; ++mi) {
#pragma unroll
    for (int r = 0; r < 16; ++r) {
      int row = bxm * 256 + wave * 64 + mi * 32 + (r & 3) + 8 * (r >> 2) + 4 * half;
      int q = acch[mi][r] * 256 + accl[mi][r];   // exact i32
      C[(size_t)row * DOUT + col] = (float)q * QINVS + bv;
    }
  }
}

// -------- LIF layer 1 (fallback path only, tc<50) --------
__global__ void lif1_kernel(const float* __restrict__ cur1, float* __restrict__ mem1,
                            uint16_t* __restrict__ PAb, float* __restrict__ hsum,
                            int tc, int init, int save_mem, int RB) {
#pragma clang fp contract(off)
  int idx = blockIdx.x * 256 + threadIdx.x;   // 131072 threads
  int b = idx & 1023;
  int h0 = (idx >> 10) * 16;
  size_t e0 = (size_t)b * DH + h0;

  float m[16], c[16], hs[16];
#pragma unroll
  for (int g = 0; g < 4; ++g) {
    float4 v = *(const float4*)(cur1 + e0 + g * 4);
    c[g * 4] = v.x; c[g * 4 + 1] = v.y; c[g * 4 + 2] = v.z; c[g * 4 + 3] = v.w;
  }
#pragma unroll
  for (int v = 0; v < 16; ++v) { m[v] = 0.0f; hs[v] = 0.0f; }
  if (!init) {
#pragma unroll
    for (int g = 0; g < 4; ++g) {
      float4 v = *(const float4*)(mem1 + e0 + g * 4);
      m[g * 4] = v.x; m[g * 4 + 1] = v.y; m[g * 4 + 2] = v.z; m[g * 4 + 3] = v.w;
    }
  }

  int kc = h0 >> 5, kh = (h0 >> 4) & 1;
  int lane = (b & 31) + 32 * kh;
  uint16_t* pab = PAb + ((size_t)kc * RB + (b >> 5)) * 64 + lane;

  for (int t = 0; t < tc; ++t) {
    uint32_t w = 0;
#pragma unroll
    for (int v = 0; v < 16; ++v) {
      float r = (m[v] > 1.0f) ? 1.0f : 0.0f;
      m[v] = 0.9f * m[v] + c[v] - r;
      bool s = (m[v] - 1.0f) > 0.0f;
      hs[v] += s ? 1.0f : 0.0f;
      w |= (s ? 1u : 0u) << v;
    }
    *pab = (uint16_t)w;
    pab += 32 * 64;
  }

  if (save_mem) {
#pragma unroll
    for (int g = 0; g < 4; ++g)
      *(float4*)(mem1 + e0 + g * 4) = make_float4(m[g * 4], m[g * 4 + 1], m[g * 4 + 2], m[g * 4 + 3]);
  }
  if (init) {
#pragma unroll
    for (int g = 0; g < 4; ++g)
      *(float4*)(hsum + e0 + g * 4) = make_float4(hs[g * 4], hs[g * 4 + 1], hs[g * 4 + 2], hs[g * 4 + 3]);
  } else {
#pragma unroll
    for (int g = 0; g < 4; ++g) {
      float4 v = *(float4*)(hsum + e0 + g * 4);
      v.x += hs[g * 4]; v.y += hs[g * 4 + 1]; v.z += hs[g * 4 + 2]; v.w += hs[g * 4 + 3];
      *(float4*)(hsum + e0 + g * 4) = v;
    }
  }
}

// -------- LIF layer 2: 4 outputs per thread, float4 loads (R14 form) --------
__global__ void lif2_kernel(const float* __restrict__ cur2, float* __restrict__ mem2,
                            float* __restrict__ osum, int tc, int init, int save_mem) {
#pragma clang fp contract(off)
  int idx = blockIdx.x * 256 + threadIdx.x;   // 65536 threads
  int e = idx * 4;
  float m[4], os[4];
  if (init) { m[0] = m[1] = m[2] = m[3] = 0.0f; }
  else { float4 v = *(const float4*)(mem2 + e); m[0] = v.x; m[1] = v.y; m[2] = v.z; m[3] = v.w; }
  os[0] = os[1] = os[2] = os[3] = 0.0f;
  for (int t = 0; t < tc; ++t) {
    float4 cv = *(const float4*)(cur2 + (size_t)t * (BATCH * DOUT) + e);
    float c[4] = {cv.x, cv.y, cv.z, cv.w};
#pragma unroll
    for (int v = 0; v < 4; ++v) {
      float r = (m[v] > 1.0f) ? 1.0f : 0.0f;
      m[v] = 0.9f * m[v] + c[v] - r;
      os[v] += ((m[v] - 1.0f) > 0.0f) ? 1.0f : 0.0f;
    }
  }
  if (save_mem) *(float4*)(mem2 + e) = make_float4(m[0], m[1], m[2], m[3]);
  if (init) {
    *(float4*)(osum + e) = make_float4(os[0], os[1], os[2], os[3]);
  } else {
    float4 v = *(float4*)(osum + e);
    v.x += os[0]; v.y += os[1]; v.z += os[2]; v.w += os[3];
    *(float4*)(osum + e) = v;
  }
}

extern "C" void kernel_launch(void* const* d_in, const int* in_sizes, int n_in,
                              void* d_out, int out_size, void* d_ws, size_t ws_size,
                              hipStream_t stream) {
  const float* x  = (const float*)d_in[0];
  const float* W1 = (const float*)d_in[1];
  const float* b1 = (const float*)d_in[2];
  const float* W2 = (const float*)d_in[3];
  const float* b2 = (const float*)d_in[4];
  float* out = (float*)d_out;           // h_sum [1024*2048] then out_sum [1024*256]
  char* ws = (char*)d_ws;

  const size_t fixed = 36 * 1024 * 1024;
  const size_t perT  = 262144 + 1048576;   // PAb bits + cur2c per time step
  int tc = 10;
  if (ws_size >= fixed + 50ull * perT) tc = 50;
  else if (ws_size >= fixed + 25ull * perT) tc = 25;
  int nchunk = TSTEPS / tc;
  int RB = tc * 32;

  size_t off = 0;
  auto alloc = [&](size_t b) { size_t p = off; off = (off + b + 255) & ~(size_t)255; return p; };
  uint16_t* PXh  = (uint16_t*)(ws + alloc(2097152));
  uint16_t* PXl  = (uint16_t*)(ws + alloc(2097152));
  uint16_t* PWh  = (uint16_t*)(ws + alloc(4194304));
  uint16_t* PWl  = (uint16_t*)(ws + alloc(4194304));
  int8_t*   PB   = (int8_t*)(ws + alloc(1048576 + 262144));          // + pipeline pad
  float*    cur1 = (float*)(ws + alloc(8388608));
  float*    mem1 = (float*)(ws + alloc(8388608));
  float*    mem2 = (float*)(ws + alloc(1048576));
  uint16_t* PAb  = (uint16_t*)(ws + alloc((size_t)tc * 262144 + 4ull * RB * 128)); // + 4-kc pad
  float*    cur2c = (float*)(ws + alloc((size_t)tc * BATCH * DOUT * 4));

  prep_kernel<<<1664, 256, 0, stream>>>(x, W1, W2, PXh, PXl, PWh, PWl, PB);

  if (nchunk == 1) {
    // fused path: 4 dispatches total
    gemm1lif_kernel<<<dim3(16, 32), 256, 0, stream>>>(PXh, PXl, PWh, PWl, b1, PAb, out, RB);
    gemm2_kernel<<<dim3((tc * BATCH) / 256, 8), 256, 0, stream>>>(PAb, PB, b2, cur2c, RB);
    lif2_kernel<<<(BATCH * DOUT) / (256 * 4), 256, 0, stream>>>(
        cur2c, mem2, out + BATCH * DH, tc, 1, 0);
  } else {
    hipMemsetAsync(mem1, 0, 8388608, stream);
    hipMemsetAsync(mem2, 0, 1048576, stream);
    gemm1_kernel<<<dim3(16, 32), 256, 0, stream>>>(PXh, PXl, PWh, PWl, b1, cur1);
    for (int c = 0; c < nchunk; ++c) {
      int init = (c == 0) ? 1 : 0;
      lif1_kernel<<<(BATCH * DH) / (256 * 16), 256, 0, stream>>>(
          cur1, mem1, PAb, out, tc, init, 1, RB);
      gemm2_kernel<<<dim3((tc * BATCH) / 256, 8), 256, 0, stream>>>(PAb, PB, b2, cur2c, RB);
      lif2_kernel<<<(BATCH * DOUT) / (256 * 4), 256, 0, stream>>>(
          cur2c, mem2, out + BATCH * DH, tc, init, 1);
    }
  }
}

// Round 22
// 186.153 us; speedup vs baseline: 1.0545x; 1.0055x over previous
//
#include <hip/hip_runtime.h>
#include <stdint.h>

// SNN: B=1024, D_IN=1024, D_H=2048, D_OUT=256, T=50, beta=0.9, thr=1.0
// cur1 time-invariant -> spk1 precomputable; layer2 = one GEMM over M = T*B.
// R22: single change vs R21/R18 -- gemm1lif pipeline depth 2->4 (static bank
// indices; never cleanly tested post-fusion). Depth-2 cover was ~232cyc vs
// 200-400cyc L2/L3 latency -> marginally uncovered, same regime R9 fixed in
// gemm2. All else frozen: prep R14, gemm2 R12-exact (floor 59us, 7x measured),
// lif2 4-out.

#define BATCH 1024
#define DIN   1024
#define DH    2048
#define DOUT  256
#define TSTEPS 50
#define QS    131072.0f          // 2^17
#define QINVS 7.62939453125e-6f  // 2^-17

typedef __bf16 bf16x8 __attribute__((ext_vector_type(8)));
typedef float  f32x4  __attribute__((ext_vector_type(4)));
typedef int    i32x4  __attribute__((ext_vector_type(4)));
typedef int    i32x16 __attribute__((ext_vector_type(16)));

__device__ __forceinline__ uint16_t f32_bf16_rne(float f) {
  uint32_t u = __float_as_uint(f);
  uint32_t r = u + 0x7FFFu + ((u >> 16) & 1u);
  return (uint16_t)(r >> 16);
}

// expand 16 spike bits -> 16 i8 bytes {0,1}; byte j = bit j
__device__ __forceinline__ i32x4 expand16(uint32_t s) {
  i32x4 r;
  r[0] = (int)((( s        & 0xFu) * 0x00204081u) & 0x01010101u);
  r[1] = (int)((((s >>  4) & 0xFu) * 0x00204081u) & 0x01010101u);
  r[2] = (int)((((s >>  8) & 0xFu) * 0x00204081u) & 0x01010101u);
  r[3] = (int)((((s >> 12) & 0xFu) * 0x00204081u) & 0x01010101u);
  return r;
}

// -------- prep: pack x,W1 splits to [k-octet][row][8bf16]; quantize W2 to PB.
// Row index lane-fast -> coalesced writes (R14). Bit-identical math.
__global__ void prep_kernel(const float* __restrict__ x, const float* __restrict__ W1,
                            const float* __restrict__ W2,
                            uint16_t* __restrict__ PXh, uint16_t* __restrict__ PXl,
                            uint16_t* __restrict__ PWh, uint16_t* __restrict__ PWl,
                            int8_t* __restrict__ PB) {
  int bid = blockIdx.x;
  if (bid < 1536) {
    const float* src;
    uint16_t *dh, *dl;
    int m, ko; size_t M;
    if (bid < 512) {
      int t = bid * 256 + threadIdx.x;        // 131072 threads
      m = t & 1023; ko = t >> 10; M = 1024;   // m fast -> coalesced writes
      src = x + (size_t)m * DIN + ko * 8;
      dh = PXh; dl = PXl;
    } else {
      int t = (bid - 512) * 256 + threadIdx.x; // 262144 threads
      m = t & 2047; ko = t >> 11; M = 2048;
      src = W1 + (size_t)m * DIN + ko * 8;
      dh = PWh; dl = PWl;
    }
    float4 a = *(const float4*)(src);
    float4 b = *(const float4*)(src + 4);
    float v[8] = {a.x, a.y, a.z, a.w, b.x, b.y, b.z, b.w};
    uint16_t h[8], l[8];
#pragma unroll
    for (int j = 0; j < 8; ++j) {
      h[j] = f32_bf16_rne(v[j]);
      l[j] = f32_bf16_rne(v[j] - __uint_as_float((uint32_t)h[j] << 16));
    }
    size_t o = ((size_t)ko * M + m) * 8;
    *(uint4*)(dh + o) = make_uint4(h[0] | (h[1] << 16), h[2] | (h[3] << 16),
                                   h[4] | (h[5] << 16), h[6] | (h[7] << 16));
    *(uint4*)(dl + o) = make_uint4(l[0] | (l[1] << 16), l[2] | (l[3] << 16),
                                   l[4] | (l[5] << 16), l[6] | (l[7] << 16));
  } else {
    int t = (bid - 1536) * 256 + threadIdx.x;  // 32768 threads
    int n = t & 255;
    int k0 = (t >> 8) * 16;
    uint32_t hw[4], lw[4];
#pragma unroll
    for (int g = 0; g < 4; ++g) {
      float4 v = *(const float4*)(W2 + (size_t)n * DH + k0 + g * 4);
      float vv[4] = {v.x, v.y, v.z, v.w};
      uint32_t hb = 0, lb = 0;
#pragma unroll
      for (int j = 0; j < 4; ++j) {
        int q = (int)rintf(vv[j] * QS);
        int h = (q + 128) >> 8;
        int l = q - (h << 8);
        hb |= ((uint32_t)(uint8_t)(int8_t)h) << (8 * j);
        lb |= ((uint32_t)(uint8_t)(int8_t)l) << (8 * j);
      }
      hw[g] = hb; lw[g] = lb;
    }
    int kc = k0 >> 5, kh = (k0 >> 4) & 1, nb = n >> 5;
    int lane = (n & 31) + 32 * kh;
    size_t off = (((size_t)(kc * 8 + nb) * 2 + 0) * 64 + lane) * 16;
    *(uint4*)(PB + off)        = make_uint4(hw[0], hw[1], hw[2], hw[3]);
    *(uint4*)(PB + off + 1024) = make_uint4(lw[0], lw[1], lw[2], lw[3]);
  }
}

// -------- FUSED GEMM1+LIF1 (tc=50): cur1 = x @ W1^T + b1 (bf16x3, zero-LDS,
// DEPTH-4 fenced pipeline -- R22 change), then LDS transpose + 50-step LIF
// recurrence per thread, emitting spike bits + h_sum. cur1 never hits global.
__global__ __launch_bounds__(256, 2) void gemm1lif_kernel(
    const uint16_t* __restrict__ PXh, const uint16_t* __restrict__ PXl,
    const uint16_t* __restrict__ PWh, const uint16_t* __restrict__ PWl,
    const float* __restrict__ bias, uint16_t* __restrict__ PAb,
    float* __restrict__ hsum, int RB) {
  __shared__ float sC[64 * 68];          // stride 68: 16B-aligned rows, 17KB
  int tid = threadIdx.x;
  int lane = tid & 63, wave = tid >> 6;
  int wm = (wave >> 1) * 32, wn = (wave & 1) * 32;
  int m0blk = blockIdx.x * 64, n0blk = blockIdx.y * 64;
  int m0 = m0blk + wm, n0 = n0blk + wn;
  int rf = lane & 15;
  int ko = lane >> 4;
  const int AK = 4 * 1024 * 8;
  const int BK = 4 * 2048 * 8;

  const uint16_t* axh = PXh + ((size_t)ko * 1024 + m0 + rf) * 8;
  const uint16_t* axl = PXl + ((size_t)ko * 1024 + m0 + rf) * 8;
  const uint16_t* bwh = PWh + ((size_t)ko * 2048 + n0 + rf) * 8;
  const uint16_t* bwl = PWl + ((size_t)ko * 2048 + n0 + rf) * 8;

  f32x4 acc[2][2] = {};
  bf16x8 ah[4][2], al[4][2], bh[4][2], bl[4][2];
#pragma unroll
  for (int s = 0; s < 4; ++s) {          // prologue: chunks 0..3
#pragma unroll
    for (int i = 0; i < 2; ++i) {
      ah[s][i] = *(const bf16x8*)(axh + i * 128);
      al[s][i] = *(const bf16x8*)(axl + i * 128);
      bh[s][i] = *(const bf16x8*)(bwh + i * 128);
      bl[s][i] = *(const bf16x8*)(bwl + i * 128);
    }
    axh += AK; axl += AK; bwh += BK; bwl += BK;
  }
  __builtin_amdgcn_sched_barrier(0);

  for (int kc0 = 0; kc0 < 32; kc0 += 4) {
#pragma unroll
    for (int u = 0; u < 4; ++u) {
#pragma unroll
      for (int i = 0; i < 2; ++i)
#pragma unroll
        for (int j = 0; j < 2; ++j) {
          acc[i][j] = __builtin_amdgcn_mfma_f32_16x16x32_bf16(ah[u][i], bh[u][j], acc[i][j], 0, 0, 0);
          acc[i][j] = __builtin_amdgcn_mfma_f32_16x16x32_bf16(ah[u][i], bl[u][j], acc[i][j], 0, 0, 0);
          acc[i][j] = __builtin_amdgcn_mfma_f32_16x16x32_bf16(al[u][i], bh[u][j], acc[i][j], 0, 0, 0);
        }
      __builtin_amdgcn_sched_barrier(0);
      // prefetch chunk kc0+u+4 into slot u (overrun reads next ws array - harmless)
#pragma unroll
      for (int i = 0; i < 2; ++i) {
        ah[u][i] = *(const bf16x8*)(axh + i * 128);
        al[u][i] = *(const bf16x8*)(axl + i * 128);
        bh[u][i] = *(const bf16x8*)(bwh + i * 128);
        bl[u][i] = *(const bf16x8*)(bwl + i * 128);
      }
      axh += AK; axl += AK; bwh += BK; bwl += BK;
      __builtin_amdgcn_sched_barrier(0);
    }
  }

  // ---- epilogue: C/D 16x16 (col=lane&15, row=(lane>>4)*4+reg) + bias -> LDS ----
  int cq = (lane >> 4) * 4;
#pragma unroll
  for (int j = 0; j < 2; ++j) {
    int colL = wn + j * 16 + rf;
    float bv = bias[n0blk + colL];
#pragma unroll
    for (int i = 0; i < 2; ++i) {
      int rowL = wm + i * 16 + cq;
#pragma unroll
      for (int r = 0; r < 4; ++r)
        sC[(rowL + r) * 68 + colL] = acc[i][j][r] + bv;
    }
  }
  __syncthreads();

  // ---- per-thread LIF recurrence: b = m0blk + (tid&63), h = n0blk + (tid>>6)*16 ----
  {
#pragma clang fp contract(off)
    int bL = tid & 63, hg = tid >> 6;
    int b = m0blk + bL;
    int h0 = n0blk + hg * 16;
    float c[16], m[16], hs[16];
#pragma unroll
    for (int g = 0; g < 4; ++g) {
      float4 v = *(const float4*)&sC[bL * 68 + hg * 16 + g * 4];
      c[g * 4] = v.x; c[g * 4 + 1] = v.y; c[g * 4 + 2] = v.z; c[g * 4 + 3] = v.w;
    }
#pragma unroll
    for (int v = 0; v < 16; ++v) { m[v] = 0.0f; hs[v] = 0.0f; }

    int kc = h0 >> 5, kh = (h0 >> 4) & 1;
    int laneP = (b & 31) + 32 * kh;
    uint16_t* pab = PAb + ((size_t)kc * RB + (b >> 5)) * 64 + laneP;

    for (int t = 0; t < TSTEPS; ++t) {
      uint32_t w = 0;
#pragma unroll
      for (int v = 0; v < 16; ++v) {
        float r = (m[v] > 1.0f) ? 1.0f : 0.0f;   // reset from PREVIOUS mem
        m[v] = 0.9f * m[v] + c[v] - r;           // contract(off): mul,add,sub like np
        bool s = (m[v] - 1.0f) > 0.0f;
        hs[v] += s ? 1.0f : 0.0f;
        w |= (s ? 1u : 0u) << v;                 // bit v = spike(h0+v)
      }
      *pab = (uint16_t)w;
      pab += 32 * 64;                            // +32 rb per t
    }
#pragma unroll
    for (int g = 0; g < 4; ++g)
      *(float4*)(hsum + (size_t)b * DH + h0 + g * 4) =
          make_float4(hs[g * 4], hs[g * 4 + 1], hs[g * 4 + 2], hs[g * 4 + 3]);
  }
}

// -------- GEMM1 (standalone, fallback path): writes cur1 --------
__global__ __launch_bounds__(256, 2) void gemm1_kernel(
    const uint16_t* __restrict__ PXh, const uint16_t* __restrict__ PXl,
    const uint16_t* __restrict__ PWh, const uint16_t* __restrict__ PWl,
    const float* __restrict__ bias, float* __restrict__ C) {
  const int N = DH;
  int tid = threadIdx.x;
  int lane = tid & 63, wave = tid >> 6;
  int wm = (wave >> 1) * 32, wn = (wave & 1) * 32;
  int m0 = blockIdx.x * 64 + wm;
  int n0 = blockIdx.y * 64 + wn;
  int rf = lane & 15;
  int ko = lane >> 4;
  const int AK = 4 * 1024 * 8;
  const int BK = 4 * 2048 * 8;

  const uint16_t* axh = PXh + ((size_t)ko * 1024 + m0 + rf) * 8;
  const uint16_t* axl = PXl + ((size_t)ko * 1024 + m0 + rf) * 8;
  const uint16_t* bwh = PWh + ((size_t)ko * 2048 + n0 + rf) * 8;
  const uint16_t* bwl = PWl + ((size_t)ko * 2048 + n0 + rf) * 8;

  f32x4 acc[2][2] = {};
  bf16x8 ah[2][2], al[2][2], bh[2][2], bl[2][2];
#pragma unroll
  for (int s = 0; s < 2; ++s) {
#pragma unroll
    for (int i = 0; i < 2; ++i) {
      ah[s][i] = *(const bf16x8*)(axh + i * 128);
      al[s][i] = *(const bf16x8*)(axl + i * 128);
      bh[s][i] = *(const bf16x8*)(bwh + i * 128);
      bl[s][i] = *(const bf16x8*)(bwl + i * 128);
    }
    axh += AK; axl += AK; bwh += BK; bwl += BK;
  }
  __builtin_amdgcn_sched_barrier(0);

  for (int kc0 = 0; kc0 < 32; kc0 += 2) {
#pragma unroll
    for (int u = 0; u < 2; ++u) {
#pragma unroll
      for (int i = 0; i < 2; ++i)
#pragma unroll
        for (int j = 0; j < 2; ++j) {
          acc[i][j] = __builtin_amdgcn_mfma_f32_16x16x32_bf16(ah[u][i], bh[u][j], acc[i][j], 0, 0, 0);
          acc[i][j] = __builtin_amdgcn_mfma_f32_16x16x32_bf16(ah[u][i], bl[u][j], acc[i][j], 0, 0, 0);
          acc[i][j] = __builtin_amdgcn_mfma_f32_16x16x32_bf16(al[u][i], bh[u][j], acc[i][j], 0, 0, 0);
        }
      __builtin_amdgcn_sched_barrier(0);
#pragma unroll
      for (int i = 0; i < 2; ++i) {
        ah[u][i] = *(const bf16x8*)(axh + i * 128);
        al[u][i] = *(const bf16x8*)(axl + i * 128);
        bh[u][i] = *(const bf16x8*)(bwh + i * 128);
        bl[u][i] = *(const bf16x8*)(bwl + i * 128);
      }
      axh += AK; axl += AK; bwh += BK; bwl += BK;
      __builtin_amdgcn_sched_barrier(0);
    }
  }

  int cq = (lane >> 4) * 4;
#pragma unroll
  for (int j = 0; j < 2; ++j) {
    int col = n0 + j * 16 + rf;
    float bv = bias[col];
#pragma unroll
    for (int i = 0; i < 2; ++i) {
      size_t row = m0 + i * 16 + cq;
      float* cp = C + row * N + col;
#pragma unroll
      for (int r = 0; r < 4; ++r) cp[(size_t)r * N] = acc[i][j][r] + bv;
    }
  }
}

// -------- GEMM2 (R12-exact, measured floor ~59us): bit-A, zero-LDS, depth-4
// fenced pipeline, wave = 64m x 32n. Block = 4 waves m-stacked = 256m x 32n
// (B block-uniform -> L1-shared). Grid (200 m, 8 nb), 3 blocks/CU.
__global__ __launch_bounds__(256, 3) void gemm2_kernel(
    const uint16_t* __restrict__ PAb, const int8_t* __restrict__ PB,
    const float* __restrict__ bias, float* __restrict__ C, int RB) {
  int tid = threadIdx.x;
  int lane = tid & 63, wave = tid >> 6;   // wave = m-quarter (64 rows)
  int bxm = blockIdx.x;                   // m-group (256 rows = 8 rb)
  int nb  = blockIdx.y;                   // n-group (32 cols)

  const uint16_t* pa = PAb + (size_t)(bxm * 8 + wave * 2) * 64 + lane;
  const int8_t*   pb = PB + ((size_t)nb * 2 * 64 + lane) * 16;
  size_t strideA = (size_t)RB * 64;       // uint16 elems per kc

  i32x16 acch[2] = {};
  i32x16 accl[2] = {};

  uint16_t abit[4][2];
  i32x4 bbh[4], bbl[4];
  i32x4 aexp[2][2];

#pragma unroll
  for (int u = 0; u < 4; ++u) {           // prologue: kc = 0..3
#pragma unroll
    for (int mi = 0; mi < 2; ++mi) abit[u][mi] = pa[mi * 64];
    bbh[u] = *(const i32x4*)(pb);
    bbl[u] = *(const i32x4*)(pb + 1024);
    pa += strideA; pb += 16384;
  }
#pragma unroll
  for (int mi = 0; mi < 2; ++mi) aexp[0][mi] = expand16(abit[0][mi]);
  __builtin_amdgcn_sched_barrier(0);

  for (int kc0 = 0; kc0 < 64; kc0 += 4) {
#pragma unroll
    for (int u = 0; u < 4; ++u) {
      const int p = u & 1;
      // expand next slot's bits (independent of this slot's MFMAs -> overlaps)
#pragma unroll
      for (int mi = 0; mi < 2; ++mi) aexp[p ^ 1][mi] = expand16(abit[(u + 1) & 3][mi]);
      // 4 MFMAs using this slot's pre-expanded A
#pragma unroll
      for (int mi = 0; mi < 2; ++mi) {
        acch[mi] = __builtin_amdgcn_mfma_i32_32x32x32_i8(aexp[p][mi], bbh[u], acch[mi], 0, 0, 0);
        accl[mi] = __builtin_amdgcn_mfma_i32_32x32x32_i8(aexp[p][mi], bbl[u], accl[mi], 0, 0, 0);
      }
      __builtin_amdgcn_sched_barrier(0);
      // prefetch kc0+u+4 into slot u (reads ws pad on the final round)
#pragma unroll
      for (int mi = 0; mi < 2; ++mi) abit[u][mi] = pa[mi * 64];
      bbh[u] = *(const i32x4*)(pb);
      bbl[u] = *(const i32x4*)(pb + 1024);
      pa += strideA; pb += 16384;
      __builtin_amdgcn_sched_barrier(0);
    }
  }

  // C/D 32x32: col = lane&31, row = (r&3) + 8*(r>>2) + 4*(lane>>5)
  int rm = lane & 31, half = lane >> 5;
  int col = nb * 32 + rm;
  float bv = bias[col];
#pragma unroll
  for (int mi = 0; mi < 2; ++mi) {
#pragma unroll
    for (int r = 0; r < 16; ++r) {
      int row = bxm * 256 + wave * 64 + mi * 32 + (r & 3) + 8 * (r >> 2) + 4 * half;
      int q = acch[mi][r] * 256 + accl[mi][r];   // exact i32
      C[(size_t)row * DOUT + col] = (float)q * QINVS + bv;
    }
  }
}

// -------- LIF layer 1 (fallback path only, tc<50) --------
__global__ void lif1_kernel(const float* __restrict__ cur1, float* __restrict__ mem1,
                            uint16_t* __restrict__ PAb, float* __restrict__ hsum,
                            int tc, int init, int save_mem, int RB) {
#pragma clang fp contract(off)
  int idx = blockIdx.x * 256 + threadIdx.x;   // 131072 threads
  int b = idx & 1023;
  int h0 = (idx >> 10) * 16;
  size_t e0 = (size_t)b * DH + h0;

  float m[16], c[16], hs[16];
#pragma unroll
  for (int g = 0; g < 4; ++g) {
    float4 v = *(const float4*)(cur1 + e0 + g * 4);
    c[g * 4] = v.x; c[g * 4 + 1] = v.y; c[g * 4 + 2] = v.z; c[g * 4 + 3] = v.w;
  }
#pragma unroll
  for (int v = 0; v < 16; ++v) { m[v] = 0.0f; hs[v] = 0.0f; }
  if (!init) {
#pragma unroll
    for (int g = 0; g < 4; ++g) {
      float4 v = *(const float4*)(mem1 + e0 + g * 4);
      m[g * 4] = v.x; m[g * 4 + 1] = v.y; m[g * 4 + 2] = v.z; m[g * 4 + 3] = v.w;
    }
  }

  int kc = h0 >> 5, kh = (h0 >> 4) & 1;
  int lane = (b & 31) + 32 * kh;
  uint16_t* pab = PAb + ((size_t)kc * RB + (b >> 5)) * 64 + lane;

  for (int t = 0; t < tc; ++t) {
    uint32_t w = 0;
#pragma unroll
    for (int v = 0; v < 16; ++v) {
      float r = (m[v] > 1.0f) ? 1.0f : 0.0f;
      m[v] = 0.9f * m[v] + c[v] - r;
      bool s = (m[v] - 1.0f) > 0.0f;
      hs[v] += s ? 1.0f : 0.0f;
      w |= (s ? 1u : 0u) << v;
    }
    *pab = (uint16_t)w;
    pab += 32 * 64;
  }

  if (save_mem) {
#pragma unroll
    for (int g = 0; g < 4; ++g)
      *(float4*)(mem1 + e0 + g * 4) = make_float4(m[g * 4], m[g * 4 + 1], m[g * 4 + 2], m[g * 4 + 3]);
  }
  if (init) {
#pragma unroll
    for (int g = 0; g < 4; ++g)
      *(float4*)(hsum + e0 + g * 4) = make_float4(hs[g * 4], hs[g * 4 + 1], hs[g * 4 + 2], hs[g * 4 + 3]);
  } else {
#pragma unroll
    for (int g = 0; g < 4; ++g) {
      float4 v = *(float4*)(hsum + e0 + g * 4);
      v.x += hs[g * 4]; v.y += hs[g * 4 + 1]; v.z += hs[g * 4 + 2]; v.w += hs[g * 4 + 3];
      *(float4*)(hsum + e0 + g * 4) = v;
    }
  }
}

// -------- LIF layer 2: 4 outputs per thread, float4 loads (R14 form) --------
__global__ void lif2_kernel(const float* __restrict__ cur2, float* __restrict__ mem2,
                            float* __restrict__ osum, int tc, int init, int save_mem) {
#pragma clang fp contract(off)
  int idx = blockIdx.x * 256 + threadIdx.x;   // 65536 threads
  int e = idx * 4;
  float m[4], os[4];
  if (init) { m[0] = m[1] = m[2] = m[3] = 0.0f; }
  else { float4 v = *(const float4*)(mem2 + e); m[0] = v.x; m[1] = v.y; m[2] = v.z; m[3] = v.w; }
  os[0] = os[1] = os[2] = os[3] = 0.0f;
  for (int t = 0; t < tc; ++t) {
    float4 cv = *(const float4*)(cur2 + (size_t)t * (BATCH * DOUT) + e);
    float c[4] = {cv.x, cv.y, cv.z, cv.w};
#pragma unroll
    for (int v = 0; v < 4; ++v) {
      float r = (m[v] > 1.0f) ? 1.0f : 0.0f;
      m[v] = 0.9f * m[v] + c[v] - r;
      os[v] += ((m[v] - 1.0f) > 0.0f) ? 1.0f : 0.0f;
    }
  }
  if (save_mem) *(float4*)(mem2 + e) = make_float4(m[0], m[1], m[2], m[3]);
  if (init) {
    *(float4*)(osum + e) = make_float4(os[0], os[1], os[2], os[3]);
  } else {
    float4 v = *(float4*)(osum + e);
    v.x += os[0]; v.y += os[1]; v.z += os[2]; v.w += os[3];
    *(float4*)(osum + e) = v;
  }
}

extern "C" void kernel_launch(void* const* d_in, const int* in_sizes, int n_in,
                              void* d_out, int out_size, void* d_ws, size_t ws_size,
                              hipStream_t stream) {
  const float* x  = (const float*)d_in[0];
  const float* W1 = (const float*)d_in[1];
  const float* b1 = (const float*)d_in[2];
  const float* W2 = (const float*)d_in[3];
  const float* b2 = (const float*)d_in[4];
  float* out = (float*)d_out;           // h_sum [1024*2048] then out_sum [1024*256]
  char* ws = (char*)d_ws;

  const size_t fixed = 36 * 1024 * 1024;
  const size_t perT  = 262144 + 1048576;   // PAb bits + cur2c per time step
  int tc = 10;
  if (ws_size >= fixed + 50ull * perT) tc = 50;
  else if (ws_size >= fixed + 25ull * perT) tc = 25;
  int nchunk = TSTEPS / tc;
  int RB = tc * 32;

  size_t off = 0;
  auto alloc = [&](size_t b) { size_t p = off; off = (off + b + 255) & ~(size_t)255; return p; };
  uint16_t* PXh  = (uint16_t*)(ws + alloc(2097152));
  uint16_t* PXl  = (uint16_t*)(ws + alloc(2097152));
  uint16_t* PWh  = (uint16_t*)(ws + alloc(4194304));
  uint16_t* PWl  = (uint16_t*)(ws + alloc(4194304));
  int8_t*   PB   = (int8_t*)(ws + alloc(1048576 + 262144));          // + pipeline pad
  float*    cur1 = (float*)(ws + alloc(8388608));
  float*    mem1 = (float*)(ws + alloc(8388608));
  float*    mem2 = (float*)(ws + alloc(1048576));
  uint16_t* PAb  = (uint16_t*)(ws + alloc((size_t)tc * 262144 + 4ull * RB * 128)); // + 4-kc pad
  float*    cur2c = (float*)(ws + alloc((size_t)tc * BATCH * DOUT * 4));

  prep_kernel<<<1664, 256, 0, stream>>>(x, W1, W2, PXh, PXl, PWh, PWl, PB);

  if (nchunk == 1) {
    // fused path: 4 dispatches total
    gemm1lif_kernel<<<dim3(16, 32), 256, 0, stream>>>(PXh, PXl, PWh, PWl, b1, PAb, out, RB);
    gemm2_kernel<<<dim3((tc * BATCH) / 256, 8), 256, 0, stream>>>(PAb, PB, b2, cur2c, RB);
    lif2_kernel<<<(BATCH * DOUT) / (256 * 4), 256, 0, stream>>>(
        cur2c, mem2, out + BATCH * DH, tc, 1, 0);
  } else {
    hipMemsetAsync(mem1, 0, 8388608, stream);
    hipMemsetAsync(mem2, 0, 1048576, stream);
    gemm1_kernel<<<dim3(16, 32), 256, 0, stream>>>(PXh, PXl, PWh, PWl, b1, cur1);
    for (int c = 0; c < nchunk; ++c) {
      int init = (c == 0) ? 1 : 0;
      lif1_kernel<<<(BATCH * DH) / (256 * 16), 256, 0, stream>>>(
          cur1, mem1, PAb, out, tc, init, 1, RB);
      gemm2_kernel<<<dim3((tc * BATCH) / 256, 8), 256, 0, stream>>>(PAb, PB, b2, cur2c, RB);
      lif2_kernel<<<(BATCH * DOUT) / (256 * 4), 256, 0, stream>>>(
          cur2c, mem2, out + BATCH * DH, tc, init, 1);
    }
  }
}